// Round 2
// baseline (1614.160 us; speedup 1.0000x reference)
//
#include <hip/hip_runtime.h>
#include <cstdint>
#include <cstddef>

#define NN 4096
#define MM 4096
#define CC 64
#define KK 32
#define INF_F __builtin_huge_valf()

// ---------------------------------------------------------------------------
// Prep: transpose support_features [B,C,M] -> ft [B,M,C]; pack masked support
// xyz into float4 (masked points pushed far away so they never enter top-32).
// ---------------------------------------------------------------------------
__global__ void pt_prep(const float* __restrict__ sf, const float* __restrict__ sxyz,
                        const int* __restrict__ smask,
                        float* __restrict__ ft, float4* __restrict__ sx4) {
  const int b = blockIdx.x >> 4;
  const int m = ((blockIdx.x & 15) << 8) + threadIdx.x;
  float v[CC];
#pragma unroll
  for (int c = 0; c < CC; ++c) v[c] = sf[((size_t)(b * CC + c)) * MM + m];
  float4* dst = (float4*)(ft + ((size_t)(b * MM + m)) * CC);
#pragma unroll
  for (int i = 0; i < CC / 4; ++i)
    dst[i] = make_float4(v[4 * i], v[4 * i + 1], v[4 * i + 2], v[4 * i + 3]);
  const size_t g = (size_t)(b * MM + m);
  float x = sxyz[g * 3 + 0], y = sxyz[g * 3 + 1], z = sxyz[g * 3 + 2];
  if (smask[g] <= 0) { x = 1e4f; y = 1e4f; z = 1e4f; }
  sx4[g] = make_float4(x, y, z, 0.0f);
}

// ---------------------------------------------------------------------------
// KNN: one wave per query. Lanes 0..31 hold the running top-32 sorted
// ascending (lane 31 = current 32nd-smallest = cmax). Insertion is a
// shuffle-up shift: ~9 ops instead of a 6-stage argmax reduce.
// ---------------------------------------------------------------------------
__global__ void pt_knn(const float* __restrict__ qxyz, const float4* __restrict__ sx4,
                       int* __restrict__ oidx, unsigned* __restrict__ ovalid,
                       int* __restrict__ onn) {
  const int lane = threadIdx.x & 63;
  const int qi = blockIdx.x * 4 + (threadIdx.x >> 6);
  const int b = qi >> 12;
  const float qx = qxyz[qi * 3 + 0];
  const float qy = qxyz[qi * 3 + 1];
  const float qz = qxyz[qi * 3 + 2];
  const float4* sb = sx4 + (size_t)b * MM;

  float sv = INF_F;   // sorted values, lanes 0..31
  int si = 0;
  float cmax = INF_F;

  for (int m0 = 0; m0 < MM; m0 += 64) {
    const float4 p = sb[m0 + lane];
    const float dx = p.x - qx, dy = p.y - qy, dz = p.z - qz;
    const float d = dx * dx + dy * dy + dz * dz;
    unsigned long long cand = __ballot(d < cmax);
    while (cand) {
      const int src = __ffsll((unsigned long long)cand) - 1;
      cand &= cand - 1;
      const float dc = __shfl(d, src);
      if (dc < cmax) {               // uniform branch
        const int im = m0 + src;
        const float up_s = __shfl_up(sv, 1);
        const int up_i = __shfl_up(si, 1);
        const bool pg = sv > dc;
        const bool pgu = (lane > 0) && (up_s > dc);
        const float ns = pg ? (pgu ? up_s : dc) : sv;
        const int ni = pg ? (pgu ? up_i : im) : si;
        if (lane < 32) { sv = ns; si = ni; }
        cmax = __shfl(sv, 31);
      }
    }
  }

  if (lane < 32) oidx[(size_t)qi * KK + lane] = si;
  const unsigned long long vb = __ballot((lane < 32) && (sv <= 0.01f));
  if (lane == 0) { ovalid[qi] = (unsigned)(vb & 0xffffffffull); onn[qi] = si; }
}

// ---------------------------------------------------------------------------
// Fused transform. Block = 256 = 4 waves; wave = 2 queries; lane = (q, k).
// All activations per-lane in registers (full unroll); LDS only for lin_i
// and BN affine (~3.3 KB). Phase order keeps peak live set at ~192 floats:
//   T1 -> DEL (T1 dies) -> XJ -> REL (XJ dies) -> R2 -> R3 -> softmax
//   -> reload XJ -> alpha + output.
// ---------------------------------------------------------------------------
__launch_bounds__(256, 2)
__global__ void pt_fused(
    const float* __restrict__ qxyz, const float4* __restrict__ sx4,
    const int* __restrict__ qmask, const float* __restrict__ ft,
    const int* __restrict__ kidx, const unsigned* __restrict__ kvalid,
    const int* __restrict__ knn_nn,
    const float* __restrict__ W1, const float* __restrict__ b1,
    const float* __restrict__ W2, const float* __restrict__ b2,
    const float* __restrict__ Wphi, const float* __restrict__ bphi,
    const float* __restrict__ Wpsi, const float* __restrict__ bpsi,
    const float* __restrict__ Wa, const float* __restrict__ ba,
    const float* __restrict__ Wg1, const float* __restrict__ bg1,
    const float* __restrict__ Wg2, const float* __restrict__ bg2,
    const float* __restrict__ gT, const float* __restrict__ beT,
    const float* __restrict__ rmT, const float* __restrict__ rvT,
    const float* __restrict__ gG, const float* __restrict__ beG,
    const float* __restrict__ rmG, const float* __restrict__ rvG,
    float* __restrict__ out) {
  __shared__ float LINB[4][2][CC];   // lin_i - bpsi, per wave/query
  __shared__ float sInvT[CC], sShT[CC], sInvG[CC], sShG[CC];

  const int wid = threadIdx.x >> 6;
  const int lane = threadIdx.x & 63;
  const int q = lane >> 5;
  const int k = lane & 31;
  const int qi = blockIdx.x * 8 + wid * 2 + q;
  const int b = qi >> 12;
  const int n = qi & (NN - 1);

  if (threadIdx.x < CC) {
    const int o = threadIdx.x;
    const float inv = gT[o] / sqrtf(rvT[o] + 1e-5f);
    sInvT[o] = inv;
    sShT[o] = beT[o] - rmT[o] * inv;
  } else if (threadIdx.x < 2 * CC) {
    const int o = threadIdx.x - CC;
    const float inv = gG[o] / sqrtf(rvG[o] + 1e-5f);
    sInvG[o] = inv;
    sShG[o] = beG[o] - rmG[o] * inv;
  }

  // ---- Phase A: lin_i - bpsi (x_i = nearest neighbor features) ----
  {
    const int nn = knn_nn[qi];
    const float* xi_p = ft + ((size_t)(b * MM + nn)) * CC;
    float XI[CC];
#pragma unroll
    for (int i = 0; i < CC / 4; ++i) {
      const float4 t = ((const float4*)xi_p)[i];
      XI[4 * i] = t.x; XI[4 * i + 1] = t.y; XI[4 * i + 2] = t.z; XI[4 * i + 3] = t.w;
    }
    const int o1 = k, o2 = k + 32;
    float a1 = bphi[o1] - bpsi[o1];
    float a2 = bphi[o2] - bpsi[o2];
    const float* r1 = Wphi + o1 * CC;
    const float* r2 = Wphi + o2 * CC;
#pragma unroll
    for (int c = 0; c < CC; ++c) { a1 += r1[c] * XI[c]; a2 += r2[c] * XI[c]; }
    LINB[wid][q][o1] = a1;
    LINB[wid][q][o2] = a2;
  }
  __syncthreads();

  // ---- Phase B: neighbor index, fmask, T1 = theta1(pos) ----
  const int kk = kidx[(size_t)qi * KK + k];
  const float fm = (float)((kvalid[qi] >> k) & 1u) + (1.0f - (float)qmask[qi]);

  float DEL[CC];
  {
    float T1[CC];
    const float qx = qxyz[qi * 3 + 0], qy = qxyz[qi * 3 + 1], qz = qxyz[qi * 3 + 2];
    const float4 pj = sx4[(size_t)b * MM + kk];
    const float p0 = (pj.x - qx) * 10.0f;
    const float p1 = (pj.y - qy) * 10.0f;
    const float p2 = (pj.z - qz) * 10.0f;
#pragma unroll
    for (int c = 0; c < CC; ++c)
      T1[c] = b1[c] + W1[c * 3 + 0] * p0 + W1[c * 3 + 1] * p1 + W1[c * 3 + 2] * p2;

    // ---- Phase C1: DEL = relu(bnT(theta2(T1))) ----  (T1 dies here)
#pragma unroll
    for (int ot = 0; ot < 8; ++ot) {
#pragma unroll
      for (int oo = 0; oo < 8; ++oo) {
        const int o = ot * 8 + oo;
        float acc = b2[o];
        const float* rt = W2 + o * CC;
#pragma unroll
        for (int c = 0; c < CC; ++c) acc += rt[c] * T1[c];
        DEL[o] = fmaxf(acc * sInvT[o] + sShT[o], 0.0f);
      }
    }
  }

  // ---- Phase C2: REL = (lin_i - bpsi) - Wpsi.x_j + DEL ----
  float REL[CC];
  {
    float XJ[CC];
    const float* xj_p = ft + ((size_t)(b * MM + kk)) * CC;
#pragma unroll
    for (int i = 0; i < CC / 4; ++i) {
      const float4 t = ((const float4*)xj_p)[i];
      XJ[4 * i] = t.x; XJ[4 * i + 1] = t.y; XJ[4 * i + 2] = t.z; XJ[4 * i + 3] = t.w;
    }
#pragma unroll
    for (int ot = 0; ot < 8; ++ot) {
#pragma unroll
      for (int oo = 0; oo < 8; ++oo) {
        const int o = ot * 8 + oo;
        float acc = 0.0f;
        const float* rp = Wpsi + o * CC;
#pragma unroll
        for (int c = 0; c < CC; ++c) acc += rp[c] * XJ[c];
        REL[o] = LINB[wid][q][o] - acc + DEL[o];
      }
    }
  }

  // ---- Phase D: R2 = gamma1(REL) ----
  float R2[CC];
#pragma unroll
  for (int ot = 0; ot < 8; ++ot) {
#pragma unroll
    for (int oo = 0; oo < 8; ++oo) {
      const int o = ot * 8 + oo;
      float acc = bg1[o];
      const float* r = Wg1 + o * CC;
#pragma unroll
      for (int c = 0; c < CC; ++c) acc += r[c] * REL[c];
      R2[o] = acc;
    }
  }

  // ---- Phase E: REL = relu(bnG(gamma2(R2))) ----
#pragma unroll
  for (int ot = 0; ot < 8; ++ot) {
#pragma unroll
    for (int oo = 0; oo < 8; ++oo) {
      const int o = ot * 8 + oo;
      float acc = bg2[o];
      const float* r = Wg2 + o * CC;
#pragma unroll
      for (int c = 0; c < CC; ++c) acc += r[c] * R2[c];
      REL[o] = fmaxf(acc * sInvG[o] + sShG[o], 0.0f);
    }
  }

  // ---- Phase F: softmax over k (32 lanes of this query's half), in place ----
#pragma unroll
  for (int o = 0; o < CC; ++o) {
    const float v = REL[o];
    float mx = v;
    mx = fmaxf(mx, __shfl_xor(mx, 1));
    mx = fmaxf(mx, __shfl_xor(mx, 2));
    mx = fmaxf(mx, __shfl_xor(mx, 4));
    mx = fmaxf(mx, __shfl_xor(mx, 8));
    mx = fmaxf(mx, __shfl_xor(mx, 16));
    const float e = __expf(v - mx);
    float s = e;
    s += __shfl_xor(s, 1);
    s += __shfl_xor(s, 2);
    s += __shfl_xor(s, 4);
    s += __shfl_xor(s, 8);
    s += __shfl_xor(s, 16);
    REL[o] = e * __builtin_amdgcn_rcpf(s);
  }

  // ---- Phase G: feats = (alpha(x_j) + DEL) * fm; out = sum_k w * feats ----
  {
    float XJ[CC];
    const float* xj_p = ft + ((size_t)(b * MM + kk)) * CC;
#pragma unroll
    for (int i = 0; i < CC / 4; ++i) {
      const float4 t = ((const float4*)xj_p)[i];
      XJ[4 * i] = t.x; XJ[4 * i + 1] = t.y; XJ[4 * i + 2] = t.z; XJ[4 * i + 3] = t.w;
    }
#pragma unroll
    for (int ot = 0; ot < 8; ++ot) {
#pragma unroll
      for (int oo = 0; oo < 8; ++oo) {
        const int o = ot * 8 + oo;
        float acc = ba[o];
        const float* ra = Wa + o * CC;
#pragma unroll
        for (int c = 0; c < CC; ++c) acc += ra[c] * XJ[c];
        float contrib = REL[o] * ((acc + DEL[o]) * fm);
        contrib += __shfl_xor(contrib, 1);
        contrib += __shfl_xor(contrib, 2);
        contrib += __shfl_xor(contrib, 4);
        contrib += __shfl_xor(contrib, 8);
        contrib += __shfl_xor(contrib, 16);
        if (k == 0) out[((size_t)(b * CC + o)) * NN + n] = contrib;
      }
    }
  }
}

// ---------------------------------------------------------------------------
extern "C" void kernel_launch(void* const* d_in, const int* in_sizes, int n_in,
                              void* d_out, int out_size, void* d_ws, size_t ws_size,
                              hipStream_t stream) {
  (void)in_sizes; (void)n_in; (void)out_size; (void)ws_size;
  const float* qxyz = (const float*)d_in[0];
  const float* sxyz = (const float*)d_in[1];
  const int* qmask = (const int*)d_in[2];
  const int* smask = (const int*)d_in[3];
  const float* sfeat = (const float*)d_in[4];
  const float* W1 = (const float*)d_in[5];
  const float* b1 = (const float*)d_in[6];
  const float* W2 = (const float*)d_in[7];
  const float* b2 = (const float*)d_in[8];
  const float* Wphi = (const float*)d_in[9];
  const float* bphi = (const float*)d_in[10];
  const float* Wpsi = (const float*)d_in[11];
  const float* bpsi = (const float*)d_in[12];
  const float* Wa = (const float*)d_in[13];
  const float* ba = (const float*)d_in[14];
  const float* Wg1 = (const float*)d_in[15];
  const float* bg1 = (const float*)d_in[16];
  const float* Wg2 = (const float*)d_in[17];
  const float* bg2 = (const float*)d_in[18];
  const float* gT = (const float*)d_in[19];
  const float* beT = (const float*)d_in[20];
  const float* rmT = (const float*)d_in[21];
  const float* rvT = (const float*)d_in[22];
  const float* gG = (const float*)d_in[23];
  const float* beG = (const float*)d_in[24];
  const float* rmG = (const float*)d_in[25];
  const float* rvG = (const float*)d_in[26];

  char* ws = (char*)d_ws;
  int* kidx = (int*)ws;                                   // 2 MB
  unsigned* kvalid = (unsigned*)(ws + 2097152);           // 64 KB
  int* knn_nn = (int*)(ws + 2097152 + 65536);             // 64 KB
  float* ft = (float*)(ws + 2097152 + 131072);            // 4 MB
  float4* sx4 = (float4*)(ws + 2097152 + 131072 + 4194304);  // 256 KB

  hipLaunchKernelGGL(pt_prep, dim3(64), dim3(256), 0, stream, sfeat, sxyz, smask, ft, sx4);
  hipLaunchKernelGGL(pt_knn, dim3(4096), dim3(256), 0, stream, qxyz, sx4, kidx, kvalid, knn_nn);
  hipLaunchKernelGGL(pt_fused, dim3(2048), dim3(256), 0, stream,
                     qxyz, sx4, qmask, ft, kidx, kvalid, knn_nn,
                     W1, b1, W2, b2, Wphi, bphi, Wpsi, bpsi, Wa, ba,
                     Wg1, bg1, Wg2, bg2, gT, beT, rmT, rvT, gG, beG, rmG, rvG,
                     (float*)d_out);
}

// Round 5
// 556.711 us; speedup vs baseline: 2.8995x; 2.8995x over previous
//
#include <hip/hip_runtime.h>
#include <cstdint>
#include <cstddef>

#define NN 4096
#define MM 4096
#define CC 64
#define KK 32
#define INF_F __builtin_huge_valf()

typedef __bf16 bf16x8 __attribute__((ext_vector_type(8)));
typedef float f32x16 __attribute__((ext_vector_type(16)));

#define NFRAG 40   // 5 convs * 2 mtiles * 4 ksteps; lo-parts live at +NFRAG

__device__ __forceinline__ f32x16 zero16() {
  f32x16 z;
#pragma unroll
  for (int i = 0; i < 16; ++i) z[i] = 0.0f;
  return z;
}

__device__ __forceinline__ void split8(const float* x, bf16x8& h, bf16x8& l) {
#pragma unroll
  for (int j = 0; j < 8; ++j) {
    const __bf16 hh = (__bf16)x[j];
    h[j] = hh;
    l[j] = (__bf16)(x[j] - (float)hh);
  }
}

// 3-term split-precision conv: acc += (Wh+Wl) * (Bh+Bl), dropping Wl*Bl.
__device__ __forceinline__ void conv_mfma(const bf16x8* __restrict__ Wf, int conv, int lane,
                                          const bf16x8* Bh, const bf16x8* Bl,
                                          f32x16& a0, f32x16& a1) {
#pragma unroll
  for (int s = 0; s < 4; ++s) {
    const int f0 = (conv * 2 + 0) * 4 + s;
    const int f1 = (conv * 2 + 1) * 4 + s;
    const bf16x8 wh0 = Wf[f0 * 64 + lane];
    const bf16x8 wh1 = Wf[f1 * 64 + lane];
    const bf16x8 wl0 = Wf[(NFRAG + f0) * 64 + lane];
    const bf16x8 wl1 = Wf[(NFRAG + f1) * 64 + lane];
    a0 = __builtin_amdgcn_mfma_f32_32x32x16_bf16(wh0, Bh[s], a0, 0, 0, 0);
    a0 = __builtin_amdgcn_mfma_f32_32x32x16_bf16(wh0, Bl[s], a0, 0, 0, 0);
    a0 = __builtin_amdgcn_mfma_f32_32x32x16_bf16(wl0, Bh[s], a0, 0, 0, 0);
    a1 = __builtin_amdgcn_mfma_f32_32x32x16_bf16(wh1, Bh[s], a1, 0, 0, 0);
    a1 = __builtin_amdgcn_mfma_f32_32x32x16_bf16(wh1, Bl[s], a1, 0, 0, 0);
    a1 = __builtin_amdgcn_mfma_f32_32x32x16_bf16(wl1, Bh[s], a1, 0, 0, 0);
  }
}

// ---------------------------------------------------------------------------
// Prep: transpose support_features [B,C,M] -> ft [B,M,C]; pack masked support
// xyz into float4 (masked points pushed far away so they never enter top-32).
// ---------------------------------------------------------------------------
__global__ void pt_prep(const float* __restrict__ sf, const float* __restrict__ sxyz,
                        const int* __restrict__ smask,
                        float* __restrict__ ft, float4* __restrict__ sx4) {
  const int b = blockIdx.x >> 4;
  const int m = ((blockIdx.x & 15) << 8) + threadIdx.x;
  float v[CC];
#pragma unroll
  for (int c = 0; c < CC; ++c) v[c] = sf[((size_t)(b * CC + c)) * MM + m];
  float4* dst = (float4*)(ft + ((size_t)(b * MM + m)) * CC);
#pragma unroll
  for (int i = 0; i < CC / 4; ++i)
    dst[i] = make_float4(v[4 * i], v[4 * i + 1], v[4 * i + 2], v[4 * i + 3]);
  const size_t g = (size_t)(b * MM + m);
  float x = sxyz[g * 3 + 0], y = sxyz[g * 3 + 1], z = sxyz[g * 3 + 2];
  if (smask[g] <= 0) { x = 1e4f; y = 1e4f; z = 1e4f; }
  sx4[g] = make_float4(x, y, z, 0.0f);
}

// ---------------------------------------------------------------------------
// Pack 5 weight matrices into bf16 A-fragments (hi at fi, lo at NFRAG+fi):
// frag fi=(conv*2+mt)*4+s, lane holds W[mt*32+(lane&31)][s*16+(lane>>5)*8+j].
// ---------------------------------------------------------------------------
__global__ void pt_pack(const float* __restrict__ Wpsi, const float* __restrict__ W2,
                        const float* __restrict__ Wg1, const float* __restrict__ Wg2,
                        const float* __restrict__ Wa, __bf16* __restrict__ Wpack) {
  const int t = blockIdx.x * 256 + threadIdx.x;
  if (t >= NFRAG * 64) return;
  const int lane = t & 63;
  const int fi = t >> 6;
  const int s = fi & 3;
  const int mt = (fi >> 2) & 1;
  const int conv = fi >> 3;
  const float* W = conv == 0 ? Wpsi : conv == 1 ? W2 : conv == 2 ? Wg1 : conv == 3 ? Wg2 : Wa;
  const int m = mt * 32 + (lane & 31);
  const int k0 = s * 16 + (lane >> 5) * 8;
  bf16x8 vh, vl;
#pragma unroll
  for (int j = 0; j < 8; ++j) {
    const float w = W[m * CC + k0 + j];
    const __bf16 h = (__bf16)w;
    vh[j] = h;
    vl[j] = (__bf16)(w - (float)h);
  }
  ((bf16x8*)Wpack)[fi * 64 + lane] = vh;
  ((bf16x8*)Wpack)[(NFRAG + fi) * 64 + lane] = vl;
}

// Pack per-channel epilogue constants: eo = {invT, shT, invG, shG}, bo = {b2, bg1, bg2, ba}
__global__ void pt_packc(const float* __restrict__ gT, const float* __restrict__ beT,
                         const float* __restrict__ rmT, const float* __restrict__ rvT,
                         const float* __restrict__ gG, const float* __restrict__ beG,
                         const float* __restrict__ rmG, const float* __restrict__ rvG,
                         const float* __restrict__ b2, const float* __restrict__ bg1,
                         const float* __restrict__ bg2, const float* __restrict__ ba,
                         float4* __restrict__ eo, float4* __restrict__ bo) {
  const int o = threadIdx.x;
  if (o >= CC) return;
  const float invT = gT[o] / sqrtf(rvT[o] + 1e-5f);
  const float invG = gG[o] / sqrtf(rvG[o] + 1e-5f);
  eo[o] = make_float4(invT, beT[o] - rmT[o] * invT, invG, beG[o] - rmG[o] * invG);
  bo[o] = make_float4(b2[o], bg1[o], bg2[o], ba[o]);
}

// ---------------------------------------------------------------------------
// KNN: one wave per query; lanes 0..31 hold the running top-32 sorted
// ascending (lane 31 = cmax). Insertion = shuffle-up shift.
// ---------------------------------------------------------------------------
__global__ void pt_knn(const float* __restrict__ qxyz, const float4* __restrict__ sx4,
                       int* __restrict__ oidx, unsigned* __restrict__ ovalid,
                       int* __restrict__ onn) {
  const int lane = threadIdx.x & 63;
  const int qi = blockIdx.x * 4 + (threadIdx.x >> 6);
  const int b = qi >> 12;
  const float qx = qxyz[qi * 3 + 0];
  const float qy = qxyz[qi * 3 + 1];
  const float qz = qxyz[qi * 3 + 2];
  const float4* sb = sx4 + (size_t)b * MM;

  float sv = INF_F;
  int si = 0;
  float cmax = INF_F;

  for (int m0 = 0; m0 < MM; m0 += 64) {
    const float4 p = sb[m0 + lane];
    const float dx = p.x - qx, dy = p.y - qy, dz = p.z - qz;
    const float d = dx * dx + dy * dy + dz * dz;
    unsigned long long cand = __ballot(d < cmax);
    while (cand) {
      const int src = __ffsll((unsigned long long)cand) - 1;
      cand &= cand - 1;
      const float dc = __shfl(d, src);
      if (dc < cmax) {
        const int im = m0 + src;
        const float up_s = __shfl_up(sv, 1);
        const int up_i = __shfl_up(si, 1);
        const bool pg = sv > dc;
        const bool pgu = (lane > 0) && (up_s > dc);
        const float ns = pg ? (pgu ? up_s : dc) : sv;
        const int ni = pg ? (pgu ? up_i : im) : si;
        if (lane < 32) { sv = ns; si = ni; }
        cmax = __shfl(sv, 31);
      }
    }
  }

  if (lane < 32) oidx[(size_t)qi * KK + lane] = si;
  const unsigned long long vb = __ballot((lane < 32) && (sv <= 0.01f));
  if (lane == 0) { ovalid[qi] = (unsigned)(vb & 0xffffffffull); onn[qi] = si; }
}

// ---------------------------------------------------------------------------
// lin pre-pass: lin[q][o] = phi(x_i)[o] + bphi[o] - bpsi[o]   (pure fp32)
// ---------------------------------------------------------------------------
__global__ void pt_lin(const float* __restrict__ ft, const int* __restrict__ knn_nn,
                       const float* __restrict__ Wphi, const float* __restrict__ bphi,
                       const float* __restrict__ bpsi, float* __restrict__ lin) {
  const int wid = threadIdx.x >> 6;
  const int lane = threadIdx.x & 63;
  const int q = blockIdx.x * 8 + wid * 2 + (lane >> 5);
  const int b = q >> 12;
  const int nn = knn_nn[q];
  const float* xi_p = ft + ((size_t)(b * MM + nn)) * CC;
  float XI[CC];
#pragma unroll
  for (int i = 0; i < CC / 4; ++i) {
    const float4 t = ((const float4*)xi_p)[i];
    XI[4 * i] = t.x; XI[4 * i + 1] = t.y; XI[4 * i + 2] = t.z; XI[4 * i + 3] = t.w;
  }
  const int o1 = lane & 31, o2 = o1 + 32;
  float a1 = bphi[o1] - bpsi[o1];
  float a2 = bphi[o2] - bpsi[o2];
  const float* r1 = Wphi + o1 * CC;
  const float* r2 = Wphi + o2 * CC;
#pragma unroll
  for (int c = 0; c < CC; ++c) { a1 += r1[c] * XI[c]; a2 += r2[c] * XI[c]; }
  lin[q * CC + o1] = a1;
  lin[q * CC + o2] = a2;
}

// ---------------------------------------------------------------------------
// Fused MFMA transform. Block 256 = 4 waves, ONE QUERY PER WAVE.
// GEMMs per query: [M=64] x [K=64] x [N=32] via v_mfma_f32_32x32x16_bf16,
// 2 M-tiles x 4 K-steps, split-precision (3 MFMA terms: WhXh+WhXl+WlXh).
// C-layout (verified): col=lane&31, row=(reg&3)+8*(reg>>2)+4*(lane>>5).
// A/B layout: m|n=lane&31, k=(lane>>5)*8+j.
//
// R4 BUG FOUND: the C->B LDS turns are CROSS-LANE (a lane reads rows it never
// wrote: writes cover bit2(row)==g, reads cover bit3(row)==g). With no
// barrier, LLVM's per-thread alias analysis proves "no alias" on the
// fully-unrolled constant indices and is free to hoist ds_reads above the
// ds_writes -> gamma2 consumed stale REL instead of R2 (deterministic
// ~3.7e-2, insensitive to precision — exactly what R3/R4 measured).
// FIX: __syncthreads() after each LDS write phase (compiler fence + HW sync).
// WAR within a turn is safe (wave lockstep: reads precede program-later writes).
// ---------------------------------------------------------------------------
__launch_bounds__(256, 2)
__global__ void pt_fused(
    const float* __restrict__ qxyz, const float4* __restrict__ sx4,
    const int* __restrict__ qmask, const float* __restrict__ ft,
    const int* __restrict__ kidx, const unsigned* __restrict__ kvalid,
    const float* __restrict__ lin,
    const float* __restrict__ W1, const float* __restrict__ b1,
    const __bf16* __restrict__ Wpack, const float4* __restrict__ eo,
    const float4* __restrict__ bo, float* __restrict__ out) {
  __shared__ float ACT[4][CC * KK];   // 32 KB, per-wave 8KB regions
  const int wid = threadIdx.x >> 6;
  const int lane = threadIdx.x & 63;
  const int g = lane >> 5;       // half: B k-group / C row-group
  const int col = lane & 31;     // B n-index / C col-index
  const int q = blockIdx.x * 4 + wid;
  const int b = q >> 12;
  const int nq = q & (NN - 1);
  float* act = ACT[wid];
  const bf16x8* Wf = (const bf16x8*)Wpack;

  // ---- neighbor id + fmask for this lane's column ----
  const int idx = kidx[q * KK + col];
  const float fm = (float)((kvalid[q] >> col) & 1u) + 1.0f - (float)qmask[q];

  // ---- XJ B-fragments (hi/lo split) ----
  bf16x8 Xh[4], Xl[4];
  {
    const float* ftq = ft + ((size_t)(b * MM + idx)) * CC;
#pragma unroll
    for (int s = 0; s < 4; ++s) {
      float xv[8];
      const float4 t0 = ((const float4*)ftq)[s * 4 + g * 2 + 0];
      const float4 t1 = ((const float4*)ftq)[s * 4 + g * 2 + 1];
      xv[0] = t0.x; xv[1] = t0.y; xv[2] = t0.z; xv[3] = t0.w;
      xv[4] = t1.x; xv[5] = t1.y; xv[6] = t1.z; xv[7] = t1.w;
      split8(xv, Xh[s], Xl[s]);
    }
  }

  // ---- DEL = relu(bnT(theta2(theta1(pos)))) in C-layout regs ----
  float DELv[32];
  {
    bf16x8 Th[4], Tl[4];
    const float qx = qxyz[q * 3 + 0], qy = qxyz[q * 3 + 1], qz = qxyz[q * 3 + 2];
    const float4 pj = sx4[(size_t)b * MM + idx];
    const float p0 = (pj.x - qx) * 10.0f;
    const float p1 = (pj.y - qy) * 10.0f;
    const float p2 = (pj.z - qz) * 10.0f;
#pragma unroll
    for (int s = 0; s < 4; ++s) {
      float tv[8];
#pragma unroll
      for (int j = 0; j < 8; ++j) {
        const int c = s * 16 + g * 8 + j;
        tv[j] = b1[c] + W1[c * 3 + 0] * p0 + W1[c * 3 + 1] * p1 + W1[c * 3 + 2] * p2;
      }
      split8(tv, Th[s], Tl[s]);
    }
    f32x16 a0 = zero16(), a1 = zero16();
    conv_mfma(Wf, 1, lane, Th, Tl, a0, a1);
#pragma unroll
    for (int mt = 0; mt < 2; ++mt)
#pragma unroll
      for (int t = 0; t < 4; ++t)
#pragma unroll
        for (int i = 0; i < 4; ++i) {
          const int r = t * 4 + i;
          const int o = mt * 32 + 4 * g + 8 * t + i;
          const float4 e = eo[o];
          const float4 bb = bo[o];
          const float v = (mt ? a1[r] : a0[r]) + bb.x;
          DELv[mt * 16 + r] = fmaxf(v * e.x + e.y, 0.0f);
        }
  }

  // ---- psi MFMA; REL = lin - psi + DEL; REL -> LDS ----
  {
    f32x16 a0 = zero16(), a1 = zero16();
    conv_mfma(Wf, 0, lane, Xh, Xl, a0, a1);
#pragma unroll
    for (int mt = 0; mt < 2; ++mt)
#pragma unroll
      for (int t = 0; t < 4; ++t) {
        const float4 lv = *(const float4*)(lin + q * CC + mt * 32 + 4 * g + 8 * t);
        const float lva[4] = {lv.x, lv.y, lv.z, lv.w};
#pragma unroll
        for (int i = 0; i < 4; ++i) {
          const int r = t * 4 + i;
          const int o = mt * 32 + 4 * g + 8 * t + i;
          act[o * KK + col] = lva[i] - (mt ? a1[r] : a0[r]) + DELv[mt * 16 + r];
        }
      }
  }
  __syncthreads();   // REL fully in LDS before cross-lane B-frag reads

  // ---- gamma1: read REL B-frags, MFMA, +bg1, write R2 to LDS ----
  {
    bf16x8 Bh[4], Bl[4];
#pragma unroll
    for (int s = 0; s < 4; ++s) {
      float xv[8];
#pragma unroll
      for (int j = 0; j < 8; ++j) xv[j] = act[(s * 16 + g * 8 + j) * KK + col];
      split8(xv, Bh[s], Bl[s]);
    }
    f32x16 a0 = zero16(), a1 = zero16();
    conv_mfma(Wf, 2, lane, Bh, Bl, a0, a1);
#pragma unroll
    for (int mt = 0; mt < 2; ++mt)
#pragma unroll
      for (int t = 0; t < 4; ++t)
#pragma unroll
        for (int i = 0; i < 4; ++i) {
          const int r = t * 4 + i;
          const int o = mt * 32 + 4 * g + 8 * t + i;
          act[o * KK + col] = (mt ? a1[r] : a0[r]) + bo[o].y;
        }
  }
  __syncthreads();   // R2 fully in LDS before cross-lane B-frag reads

  // ---- gamma2 (from R2 frags) + alpha (from X frags) MFMAs ----
  f32x16 h0 = zero16(), h1 = zero16();   // gamma2 out
  {
    bf16x8 Bh[4], Bl[4];
#pragma unroll
    for (int s = 0; s < 4; ++s) {
      float xv[8];
#pragma unroll
      for (int j = 0; j < 8; ++j) xv[j] = act[(s * 16 + g * 8 + j) * KK + col];
      split8(xv, Bh[s], Bl[s]);
    }
    conv_mfma(Wf, 3, lane, Bh, Bl, h0, h1);
  }
  f32x16 fa0 = zero16(), fa1 = zero16(); // alpha out
  conv_mfma(Wf, 4, lane, Xh, Xl, fa0, fa1);

  // ---- epilogue: bnG+relu -> softmax over n -> weighted sum -> store ----
#pragma unroll
  for (int mt = 0; mt < 2; ++mt)
#pragma unroll
    for (int t = 0; t < 4; ++t)
#pragma unroll
      for (int i = 0; i < 4; ++i) {
        const int r = t * 4 + i;
        const int o = mt * 32 + 4 * g + 8 * t + i;
        const float4 e = eo[o];
        const float4 bb = bo[o];
        float v = ((mt ? h1[r] : h0[r]) + bb.z) * e.z + e.w;
        v = fmaxf(v, 0.0f);
        float mx = v;
        mx = fmaxf(mx, __shfl_xor(mx, 1));
        mx = fmaxf(mx, __shfl_xor(mx, 2));
        mx = fmaxf(mx, __shfl_xor(mx, 4));
        mx = fmaxf(mx, __shfl_xor(mx, 8));
        mx = fmaxf(mx, __shfl_xor(mx, 16));
        const float ex = __expf(v - mx);
        float sm = ex;
        sm += __shfl_xor(sm, 1);
        sm += __shfl_xor(sm, 2);
        sm += __shfl_xor(sm, 4);
        sm += __shfl_xor(sm, 8);
        sm += __shfl_xor(sm, 16);
        const float w = ex * __builtin_amdgcn_rcpf(sm);
        const float feats = ((mt ? fa1[r] : fa0[r]) + bb.w + DELv[mt * 16 + r]) * fm;
        float contrib = w * feats;
        contrib += __shfl_xor(contrib, 1);
        contrib += __shfl_xor(contrib, 2);
        contrib += __shfl_xor(contrib, 4);
        contrib += __shfl_xor(contrib, 8);
        contrib += __shfl_xor(contrib, 16);
        if (col == 0) out[((size_t)(b * CC + o)) * NN + nq] = contrib;
      }
}

// ---------------------------------------------------------------------------
extern "C" void kernel_launch(void* const* d_in, const int* in_sizes, int n_in,
                              void* d_out, int out_size, void* d_ws, size_t ws_size,
                              hipStream_t stream) {
  (void)in_sizes; (void)n_in; (void)out_size; (void)ws_size;
  const float* qxyz = (const float*)d_in[0];
  const float* sxyz = (const float*)d_in[1];
  const int* qmask = (const int*)d_in[2];
  const int* smask = (const int*)d_in[3];
  const float* sfeat = (const float*)d_in[4];
  const float* W1 = (const float*)d_in[5];
  const float* b1 = (const float*)d_in[6];
  const float* W2 = (const float*)d_in[7];
  const float* b2 = (const float*)d_in[8];
  const float* Wphi = (const float*)d_in[9];
  const float* bphi = (const float*)d_in[10];
  const float* Wpsi = (const float*)d_in[11];
  const float* bpsi = (const float*)d_in[12];
  const float* Wa = (const float*)d_in[13];
  const float* ba = (const float*)d_in[14];
  const float* Wg1 = (const float*)d_in[15];
  const float* bg1 = (const float*)d_in[16];
  const float* Wg2 = (const float*)d_in[17];
  const float* bg2 = (const float*)d_in[18];
  const float* gT = (const float*)d_in[19];
  const float* beT = (const float*)d_in[20];
  const float* rmT = (const float*)d_in[21];
  const float* rvT = (const float*)d_in[22];
  const float* gG = (const float*)d_in[23];
  const float* beG = (const float*)d_in[24];
  const float* rmG = (const float*)d_in[25];
  const float* rvG = (const float*)d_in[26];

  char* ws = (char*)d_ws;
  int* kidx      = (int*)(ws + 0);                    // 2 MB
  unsigned* kval = (unsigned*)(ws + 2097152);         // 64 KB
  int* knn_nn    = (int*)(ws + 2162688);              // 64 KB
  float* ft      = (float*)(ws + 2228224);            // 4 MB
  float4* sx4    = (float4*)(ws + 6422528);           // 256 KB
  float* lin     = (float*)(ws + 6684672);            // 4 MB
  __bf16* Wpack  = (__bf16*)(ws + 10878976);          // 80 KB (hi 40 + lo 40)
  float4* eo     = (float4*)(ws + 10960896);          // 1 KB
  float4* bo     = (float4*)(ws + 10961920);          // 1 KB

  hipLaunchKernelGGL(pt_prep, dim3(64), dim3(256), 0, stream, sfeat, sxyz, smask, ft, sx4);
  hipLaunchKernelGGL(pt_pack, dim3(10), dim3(256), 0, stream, Wpsi, W2, Wg1, Wg2, Wa, Wpack);
  hipLaunchKernelGGL(pt_packc, dim3(1), dim3(64), 0, stream,
                     gT, beT, rmT, rvT, gG, beG, rmG, rvG, b2, bg1, bg2, ba, eo, bo);
  hipLaunchKernelGGL(pt_knn, dim3(4096), dim3(256), 0, stream, qxyz, sx4, kidx, kval, knn_nn);
  hipLaunchKernelGGL(pt_lin, dim3(2048), dim3(256), 0, stream, ft, knn_nn, Wphi, bphi, bpsi, lin);
  hipLaunchKernelGGL(pt_fused, dim3(4096), dim3(256), 0, stream,
                     qxyz, sx4, qmask, ft, kidx, kval, lin,
                     W1, b1, Wpack, eo, bo, (float*)d_out);
}

// Round 7
// 444.774 us; speedup vs baseline: 3.6292x; 1.2517x over previous
//
#include <hip/hip_runtime.h>
#include <cstdint>
#include <cstddef>

#define NN 4096
#define MM 4096
#define CC 64
#define KK 32
#define INF_F __builtin_huge_valf()

typedef __bf16 bf16x8 __attribute__((ext_vector_type(8)));
typedef __bf16 bf16x4 __attribute__((ext_vector_type(4)));
typedef float f32x16 __attribute__((ext_vector_type(16)));

#define NFRAG 40   // 5 convs * 2 mtiles * 4 ksteps; lo-parts live at +NFRAG
#define ASTRIDE 68 // LDS act row stride in bf16 elems: 2-way bank phase (free), 8B-aligned

__device__ __forceinline__ f32x16 zero16() {
  f32x16 z;
#pragma unroll
  for (int i = 0; i < 16; ++i) z[i] = 0.0f;
  return z;
}

// 2-term split-W conv: acc += (Wh + Wl) * B   (B is plain bf16 activation).
__device__ __forceinline__ void conv2(const bf16x8* __restrict__ Wf, int conv, int lane,
                                      const bf16x8* B4, f32x16& a0, f32x16& a1) {
#pragma unroll
  for (int s = 0; s < 4; ++s) {
    const int f0 = (conv * 2 + 0) * 4 + s;
    const int f1 = (conv * 2 + 1) * 4 + s;
    const bf16x8 wh0 = Wf[f0 * 64 + lane];
    const bf16x8 wh1 = Wf[f1 * 64 + lane];
    const bf16x8 wl0 = Wf[(NFRAG + f0) * 64 + lane];
    const bf16x8 wl1 = Wf[(NFRAG + f1) * 64 + lane];
    a0 = __builtin_amdgcn_mfma_f32_32x32x16_bf16(wh0, B4[s], a0, 0, 0, 0);
    a0 = __builtin_amdgcn_mfma_f32_32x32x16_bf16(wl0, B4[s], a0, 0, 0, 0);
    a1 = __builtin_amdgcn_mfma_f32_32x32x16_bf16(wh1, B4[s], a1, 0, 0, 0);
    a1 = __builtin_amdgcn_mfma_f32_32x32x16_bf16(wl1, B4[s], a1, 0, 0, 0);
  }
}

// ---------------------------------------------------------------------------
// Prep: transpose support_features [B,C,M] -> ftb [B,M,C] in bf16; pack
// masked support xyz into float4 (masked points pushed far away).
// NOTE (R6 lesson): total d_ws footprint must stay <= ~10.9 MB (proven safe
// through R5); R6's extra 2 MB overflowed ws and corrupted adjacent device
// allocations -> post-timing divergence. fp32 ft dropped; pt_lin reads bf16.
// ---------------------------------------------------------------------------
__global__ void pt_prep(const float* __restrict__ sf, const float* __restrict__ sxyz,
                        const int* __restrict__ smask,
                        __bf16* __restrict__ ftb, float4* __restrict__ sx4) {
  const int b = blockIdx.x >> 4;
  const int m = ((blockIdx.x & 15) << 8) + threadIdx.x;
  float v[CC];
#pragma unroll
  for (int c = 0; c < CC; ++c) v[c] = sf[((size_t)(b * CC + c)) * MM + m];
  bf16x8* db = (bf16x8*)(ftb + ((size_t)(b * MM + m)) * CC);
#pragma unroll
  for (int i = 0; i < CC / 8; ++i) {
    bf16x8 t;
#pragma unroll
    for (int j = 0; j < 8; ++j) t[j] = (__bf16)v[8 * i + j];
    db[i] = t;
  }
  const size_t g = (size_t)(b * MM + m);
  float x = sxyz[g * 3 + 0], y = sxyz[g * 3 + 1], z = sxyz[g * 3 + 2];
  if (smask[g] <= 0) { x = 1e4f; y = 1e4f; z = 1e4f; }
  sx4[g] = make_float4(x, y, z, 0.0f);
}

// ---------------------------------------------------------------------------
// Pack 5 weight matrices into bf16 A-fragments (hi at fi, lo at NFRAG+fi):
// frag fi=(conv*2+mt)*4+s, lane holds W[mt*32+(lane&31)][s*16+(lane>>5)*8+j].
// ---------------------------------------------------------------------------
__global__ void pt_pack(const float* __restrict__ Wpsi, const float* __restrict__ W2,
                        const float* __restrict__ Wg1, const float* __restrict__ Wg2,
                        const float* __restrict__ Wa, __bf16* __restrict__ Wpack) {
  const int t = blockIdx.x * 256 + threadIdx.x;
  if (t >= NFRAG * 64) return;
  const int lane = t & 63;
  const int fi = t >> 6;
  const int s = fi & 3;
  const int mt = (fi >> 2) & 1;
  const int conv = fi >> 3;
  const float* W = conv == 0 ? Wpsi : conv == 1 ? W2 : conv == 2 ? Wg1 : conv == 3 ? Wg2 : Wa;
  const int m = mt * 32 + (lane & 31);
  const int k0 = s * 16 + (lane >> 5) * 8;
  bf16x8 vh, vl;
#pragma unroll
  for (int j = 0; j < 8; ++j) {
    const float w = W[m * CC + k0 + j];
    const __bf16 h = (__bf16)w;
    vh[j] = h;
    vl[j] = (__bf16)(w - (float)h);
  }
  ((bf16x8*)Wpack)[fi * 64 + lane] = vh;
  ((bf16x8*)Wpack)[(NFRAG + fi) * 64 + lane] = vl;
}

// Pack per-channel epilogue constants: eo = {invT, shT, invG, shG}, bo = {b2, bg1, bg2, ba}
__global__ void pt_packc(const float* __restrict__ gT, const float* __restrict__ beT,
                         const float* __restrict__ rmT, const float* __restrict__ rvT,
                         const float* __restrict__ gG, const float* __restrict__ beG,
                         const float* __restrict__ rmG, const float* __restrict__ rvG,
                         const float* __restrict__ b2, const float* __restrict__ bg1,
                         const float* __restrict__ bg2, const float* __restrict__ ba,
                         float4* __restrict__ eo, float4* __restrict__ bo) {
  const int o = threadIdx.x;
  if (o >= CC) return;
  const float invT = gT[o] / sqrtf(rvT[o] + 1e-5f);
  const float invG = gG[o] / sqrtf(rvG[o] + 1e-5f);
  eo[o] = make_float4(invT, beT[o] - rmT[o] * invT, invG, beG[o] - rmG[o] * invG);
  bo[o] = make_float4(b2[o], bg1[o], bg2[o], ba[o]);
}

// ---------------------------------------------------------------------------
// KNN: one wave per query. Chunk 0 (64 pts) seeds the top-32 via a full
// 64-lane bitonic sort; remaining 63 chunks: prefetched loads + ballot +
// sorted shuffle-up insert (lanes 0..31 = running top-32; lane 31 = cmax).
// ---------------------------------------------------------------------------
__global__ void pt_knn(const float* __restrict__ qxyz, const float4* __restrict__ sx4,
                       int* __restrict__ oidx, unsigned* __restrict__ ovalid,
                       int* __restrict__ onn) {
  const int lane = threadIdx.x & 63;
  const int qi = blockIdx.x * 4 + (threadIdx.x >> 6);
  const int b = qi >> 12;
  const float qx = qxyz[qi * 3 + 0];
  const float qy = qxyz[qi * 3 + 1];
  const float qz = qxyz[qi * 3 + 2];
  const float4* sb = sx4 + (size_t)b * MM;

  float sv;
  int si;
  {
    const float4 p = sb[lane];
    const float dx = p.x - qx, dy = p.y - qy, dz = p.z - qz;
    float v = dx * dx + dy * dy + dz * dz;
    int id = lane;
#pragma unroll
    for (int k = 2; k <= 64; k <<= 1) {
#pragma unroll
      for (int j = k >> 1; j > 0; j >>= 1) {
        const float ov = __shfl_xor(v, j);
        const int oi = __shfl_xor(id, j);
        const bool up = ((lane & k) == 0);
        const bool lower = ((lane & j) == 0);
        const bool take = (up == lower) ? (ov < v) : (ov > v);
        if (take) { v = ov; id = oi; }
      }
    }
    sv = v; si = id;
  }
  float cmax = __shfl(sv, 31);

  float4 p = sb[64 + lane];
  for (int m0 = 64; m0 < MM; m0 += 64) {
    const int mn = (m0 + 64 < MM) ? (m0 + 64) : 64;
    const float4 pn = sb[mn + lane];
    const float dx = p.x - qx, dy = p.y - qy, dz = p.z - qz;
    const float d = dx * dx + dy * dy + dz * dz;
    unsigned long long cand = __ballot(d < cmax);
    while (cand) {
      const int src = __ffsll((unsigned long long)cand) - 1;
      cand &= cand - 1;
      const float dc = __shfl(d, src);
      if (dc < cmax) {               // uniform branch
        const int im = m0 + src;
        const float up_s = __shfl_up(sv, 1);
        const int up_i = __shfl_up(si, 1);
        const bool pg = sv > dc;
        const bool pgu = (lane > 0) && (up_s > dc);
        const float ns = pg ? (pgu ? up_s : dc) : sv;
        const int ni = pg ? (pgu ? up_i : im) : si;
        if (lane < 32) { sv = ns; si = ni; }
        cmax = __shfl(sv, 31);
      }
    }
    p = pn;
  }

  if (lane < 32) oidx[(size_t)qi * KK + lane] = si;
  const unsigned long long vb = __ballot((lane < 32) && (sv <= 0.01f));
  if (lane == 0) { ovalid[qi] = (unsigned)(vb & 0xffffffffull); onn[qi] = si; }
}

// ---------------------------------------------------------------------------
// lin pre-pass: lin[q][o] = phi(x_i)[o] + bphi[o] - bpsi[o]
// x_i read from bf16 ftb (err ~5e-4 into lin — negligible vs 1.5e-2 budget).
// ---------------------------------------------------------------------------
__global__ void pt_lin(const __bf16* __restrict__ ftb, const int* __restrict__ knn_nn,
                       const float* __restrict__ Wphi, const float* __restrict__ bphi,
                       const float* __restrict__ bpsi, float* __restrict__ lin) {
  const int wid = threadIdx.x >> 6;
  const int lane = threadIdx.x & 63;
  const int q = blockIdx.x * 8 + wid * 2 + (lane >> 5);
  const int b = q >> 12;
  const int nn = knn_nn[q];
  const __bf16* xi_p = ftb + ((size_t)(b * MM + nn)) * CC;
  float XI[CC];
#pragma unroll
  for (int i = 0; i < CC / 8; ++i) {
    const bf16x8 t = ((const bf16x8*)xi_p)[i];
#pragma unroll
    for (int j = 0; j < 8; ++j) XI[8 * i + j] = (float)t[j];
  }
  const int o1 = lane & 31, o2 = o1 + 32;
  float a1 = bphi[o1] - bpsi[o1];
  float a2 = bphi[o2] - bpsi[o2];
  const float* r1 = Wphi + o1 * CC;
  const float* r2 = Wphi + o2 * CC;
#pragma unroll
  for (int c = 0; c < CC; ++c) { a1 += r1[c] * XI[c]; a2 += r2[c] * XI[c]; }
  lin[q * CC + o1] = a1;
  lin[q * CC + o2] = a2;
}

// ---------------------------------------------------------------------------
// Fused MFMA transform. Block 256 = 4 waves, ONE QUERY PER WAVE.
// Per conv: [M=64]x[K=64]x[N=32] via v_mfma_f32_32x32x16_bf16, 2 M-tiles x
// 4 K-steps x 2 W-terms (Wh+Wl, plain-bf16 activations) = 16 MFMA.
// C-layout (verified): col=lane&31, row=(reg&3)+8*(reg>>2)+4*(lane>>5).
// A/B layout: m|n=lane&31, k=(lane>>5)*8+j.
// LDS turns store activations as bf16 in TRANSPOSED [col][o] layout
// (stride 68: 2-way bank phase = free; b64-aligned). Cross-lane turns
// require __syncthreads() after each write phase (R4 lesson).
// ---------------------------------------------------------------------------
__launch_bounds__(256, 2)
__global__ void pt_fused(
    const float* __restrict__ qxyz, const float4* __restrict__ sx4,
    const int* __restrict__ qmask, const __bf16* __restrict__ ftb,
    const int* __restrict__ kidx, const unsigned* __restrict__ kvalid,
    const float* __restrict__ lin,
    const float* __restrict__ W1, const float* __restrict__ b1,
    const __bf16* __restrict__ Wpack, const float4* __restrict__ eo,
    const float4* __restrict__ bo, float* __restrict__ out) {
  __shared__ __bf16 ACT2[4][32 * ASTRIDE];  // 4 x 4352 B = 17.4 KB
  __shared__ float4 sEO[CC], sBO[CC];
  const int wid = threadIdx.x >> 6;
  const int lane = threadIdx.x & 63;
  const int g = lane >> 5;       // half: B k-group / C row-group
  const int col = lane & 31;     // B n-index / C col-index
  const int q = blockIdx.x * 4 + wid;
  const int b = q >> 12;
  const int nq = q & (NN - 1);
  __bf16* act = ACT2[wid];
  const bf16x8* Wf = (const bf16x8*)Wpack;

  if (threadIdx.x < CC) { sEO[threadIdx.x] = eo[threadIdx.x]; sBO[threadIdx.x] = bo[threadIdx.x]; }

  // ---- neighbor id + fmask for this lane's column ----
  const int idx = kidx[q * KK + col];
  const float fm = (float)((kvalid[q] >> col) & 1u) + 1.0f - (float)qmask[q];

  // ---- XJ B-fragments: direct bf16 loads ----
  bf16x8 Xb[4];
  {
    const __bf16* ftq = ftb + ((size_t)(b * MM + idx)) * CC;
#pragma unroll
    for (int s = 0; s < 4; ++s) Xb[s] = *(const bf16x8*)(ftq + s * 16 + g * 8);
  }

  // ---- T1 = theta1(pos) -> bf16 B-frags ----
  bf16x8 Tb[4];
  {
    const float qx = qxyz[q * 3 + 0], qy = qxyz[q * 3 + 1], qz = qxyz[q * 3 + 2];
    const float4 pj = sx4[(size_t)b * MM + idx];
    const float p0 = (pj.x - qx) * 10.0f;
    const float p1 = (pj.y - qy) * 10.0f;
    const float p2 = (pj.z - qz) * 10.0f;
#pragma unroll
    for (int s = 0; s < 4; ++s) {
      bf16x8 t;
#pragma unroll
      for (int j = 0; j < 8; ++j) {
        const int c = s * 16 + g * 8 + j;
        t[j] = (__bf16)(b1[c] + W1[c * 3 + 0] * p0 + W1[c * 3 + 1] * p1 + W1[c * 3 + 2] * p2);
      }
      Tb[s] = t;
    }
  }
  __syncthreads();   // sEO/sBO visible

  // ---- theta2 + psi convs (4 independent MFMA chains) ----
  float DELv[32];
  {
    f32x16 aT0 = zero16(), aT1 = zero16(), aP0 = zero16(), aP1 = zero16();
    conv2(Wf, 1, lane, Tb, aT0, aT1);   // theta2(T1)
    conv2(Wf, 0, lane, Xb, aP0, aP1);   // psi(x_j)
#pragma unroll
    for (int mt = 0; mt < 2; ++mt)
#pragma unroll
      for (int t = 0; t < 4; ++t) {
        const int ob = mt * 32 + 8 * t + 4 * g;
        const float4 lv = *(const float4*)(lin + q * CC + ob);
        const float lva[4] = {lv.x, lv.y, lv.z, lv.w};
        bf16x4 w;
#pragma unroll
        for (int i = 0; i < 4; ++i) {
          const int r = t * 4 + i;
          const int o = ob + i;
          const float4 e = sEO[o];
          const float dv = fmaxf(((mt ? aT1[r] : aT0[r]) + sBO[o].x) * e.x + e.y, 0.0f);
          DELv[mt * 16 + r] = dv;
          w[i] = (__bf16)(lva[i] - (mt ? aP1[r] : aP0[r]) + dv);   // REL
        }
        *(bf16x4*)(act + col * ASTRIDE + ob) = w;
      }
  }
  __syncthreads();   // REL fully in LDS before cross-lane B-frag reads

  // ---- gamma1 (REL frags) + alpha (X frags) convs, interleaved ----
  f32x16 fa0 = zero16(), fa1 = zero16();
  {
    bf16x8 Rb[4];
#pragma unroll
    for (int s = 0; s < 4; ++s) {
      const bf16x4 lo = *(const bf16x4*)(act + col * ASTRIDE + s * 16 + g * 8);
      const bf16x4 hi = *(const bf16x4*)(act + col * ASTRIDE + s * 16 + g * 8 + 4);
      Rb[s] = bf16x8{lo[0], lo[1], lo[2], lo[3], hi[0], hi[1], hi[2], hi[3]};
    }
    f32x16 a0 = zero16(), a1 = zero16();
    conv2(Wf, 2, lane, Rb, a0, a1);     // gamma1
    conv2(Wf, 4, lane, Xb, fa0, fa1);   // alpha
#pragma unroll
    for (int mt = 0; mt < 2; ++mt)
#pragma unroll
      for (int t = 0; t < 4; ++t) {
        const int ob = mt * 32 + 8 * t + 4 * g;
        bf16x4 w;
#pragma unroll
        for (int i = 0; i < 4; ++i) {
          const int r = t * 4 + i;
          w[i] = (__bf16)((mt ? a1[r] : a0[r]) + sBO[ob + i].y);   // R2
        }
        *(bf16x4*)(act + col * ASTRIDE + ob) = w;
      }
  }
  __syncthreads();   // R2 fully in LDS before cross-lane B-frag reads

  // ---- gamma2 conv ----
  f32x16 h0 = zero16(), h1 = zero16();
  {
    bf16x8 Rb[4];
#pragma unroll
    for (int s = 0; s < 4; ++s) {
      const bf16x4 lo = *(const bf16x4*)(act + col * ASTRIDE + s * 16 + g * 8);
      const bf16x4 hi = *(const bf16x4*)(act + col * ASTRIDE + s * 16 + g * 8 + 4);
      Rb[s] = bf16x8{lo[0], lo[1], lo[2], lo[3], hi[0], hi[1], hi[2], hi[3]};
    }
    conv2(Wf, 3, lane, Rb, h0, h1);
  }

  // ---- epilogue: bnG+relu -> softmax over n -> weighted sum -> store ----
#pragma unroll
  for (int mt = 0; mt < 2; ++mt)
#pragma unroll
    for (int t = 0; t < 4; ++t)
#pragma unroll
      for (int i = 0; i < 4; ++i) {
        const int r = t * 4 + i;
        const int o = mt * 32 + 4 * g + 8 * t + i;
        const float4 e = sEO[o];
        const float4 bb = sBO[o];
        float v = ((mt ? h1[r] : h0[r]) + bb.z) * e.z + e.w;
        v = fmaxf(v, 0.0f);
        float mx = v;
        mx = fmaxf(mx, __shfl_xor(mx, 1));
        mx = fmaxf(mx, __shfl_xor(mx, 2));
        mx = fmaxf(mx, __shfl_xor(mx, 4));
        mx = fmaxf(mx, __shfl_xor(mx, 8));
        mx = fmaxf(mx, __shfl_xor(mx, 16));
        const float ex = __expf(v - mx);
        float sm = ex;
        sm += __shfl_xor(sm, 1);
        sm += __shfl_xor(sm, 2);
        sm += __shfl_xor(sm, 4);
        sm += __shfl_xor(sm, 8);
        sm += __shfl_xor(sm, 16);
        const float w = ex * __builtin_amdgcn_rcpf(sm);
        const float feats = ((mt ? fa1[r] : fa0[r]) + bb.w + DELv[mt * 16 + r]) * fm;
        float contrib = w * feats;
        contrib += __shfl_xor(contrib, 1);
        contrib += __shfl_xor(contrib, 2);
        contrib += __shfl_xor(contrib, 4);
        contrib += __shfl_xor(contrib, 8);
        contrib += __shfl_xor(contrib, 16);
        if (col == 0) out[((size_t)(b * CC + o)) * NN + nq] = contrib;
      }
}

// ---------------------------------------------------------------------------
extern "C" void kernel_launch(void* const* d_in, const int* in_sizes, int n_in,
                              void* d_out, int out_size, void* d_ws, size_t ws_size,
                              hipStream_t stream) {
  (void)in_sizes; (void)n_in; (void)out_size; (void)ws_size;
  const float* qxyz = (const float*)d_in[0];
  const float* sxyz = (const float*)d_in[1];
  const int* qmask = (const int*)d_in[2];
  const int* smask = (const int*)d_in[3];
  const float* sfeat = (const float*)d_in[4];
  const float* W1 = (const float*)d_in[5];
  const float* b1 = (const float*)d_in[6];
  const float* W2 = (const float*)d_in[7];
  const float* b2 = (const float*)d_in[8];
  const float* Wphi = (const float*)d_in[9];
  const float* bphi = (const float*)d_in[10];
  const float* Wpsi = (const float*)d_in[11];
  const float* bpsi = (const float*)d_in[12];
  const float* Wa = (const float*)d_in[13];
  const float* ba = (const float*)d_in[14];
  const float* Wg1 = (const float*)d_in[15];
  const float* bg1 = (const float*)d_in[16];
  const float* Wg2 = (const float*)d_in[17];
  const float* bg2 = (const float*)d_in[18];
  const float* gT = (const float*)d_in[19];
  const float* beT = (const float*)d_in[20];
  const float* rmT = (const float*)d_in[21];
  const float* rvT = (const float*)d_in[22];
  const float* gG = (const float*)d_in[23];
  const float* beG = (const float*)d_in[24];
  const float* rmG = (const float*)d_in[25];
  const float* rvG = (const float*)d_in[26];

  // Total footprint 8.87 MB — must stay <= ~10.9 MB (proven ws bound, R6 lesson).
  char* ws = (char*)d_ws;
  int* kidx      = (int*)(ws + 0);                    // 2 MB
  unsigned* kval = (unsigned*)(ws + 2097152);         // 64 KB
  int* knn_nn    = (int*)(ws + 2162688);              // 64 KB
  __bf16* ftb    = (__bf16*)(ws + 2228224);           // 2 MB (bf16 features)
  float4* sx4    = (float4*)(ws + 4325376);           // 256 KB
  float* lin     = (float*)(ws + 4587520);            // 4 MB
  __bf16* Wpack  = (__bf16*)(ws + 8781824);           // 80 KB (hi 40 + lo 40)
  float4* eo     = (float4*)(ws + 8863744);           // 1 KB
  float4* bo     = (float4*)(ws + 8864768);           // 1 KB -> end 8865792

  hipLaunchKernelGGL(pt_prep, dim3(64), dim3(256), 0, stream, sfeat, sxyz, smask, ftb, sx4);
  hipLaunchKernelGGL(pt_pack, dim3(10), dim3(256), 0, stream, Wpsi, W2, Wg1, Wg2, Wa, Wpack);
  hipLaunchKernelGGL(pt_packc, dim3(1), dim3(64), 0, stream,
                     gT, beT, rmT, rvT, gG, beG, rmG, rvG, b2, bg1, bg2, ba, eo, bo);
  hipLaunchKernelGGL(pt_knn, dim3(4096), dim3(256), 0, stream, qxyz, sx4, kidx, kval, knn_nn);
  hipLaunchKernelGGL(pt_lin, dim3(2048), dim3(256), 0, stream, ftb, knn_nn, Wphi, bphi, bpsi, lin);
  hipLaunchKernelGGL(pt_fused, dim3(4096), dim3(256), 0, stream,
                     qxyz, sx4, qmask, ftb, kidx, kval, lin,
                     W1, b1, Wpack, eo, bo, (float*)d_out);
}